// Round 20
// baseline (337.498 us; speedup 1.0000x reference)
//
#include <hip/hip_runtime.h>

typedef unsigned short u16;
typedef __bf16 bf16x8 __attribute__((ext_vector_type(8)));
typedef float f32x4 __attribute__((ext_vector_type(4)));

#define LOG2E 1.44269504088896f

// ---- helpers -------------------------------------------------------------

__device__ __forceinline__ u16 f2bf(float f) {
  unsigned u = __float_as_uint(f);
  u += 0x7fffu + ((u >> 16) & 1u);   // RNE
  return (u16)(u >> 16);
}
__device__ __forceinline__ float bf2f(u16 h) {
  return __uint_as_float(((unsigned)h) << 16);
}

__device__ __forceinline__ void gload16(const void* g, void* l) {
  __builtin_amdgcn_global_load_lds(
      (const __attribute__((address_space(1))) unsigned int*)g,
      (__attribute__((address_space(3))) unsigned int*)l, 16, 0, 0);
}

// ---- kernel 1: f32 -> bf16 copy ------------------------------------------

__global__ __launch_bounds__(256) void k_cvt_x(const float* __restrict__ src,
                                               u16* __restrict__ dst, int n4) {
  int i = blockIdx.x * blockDim.x + threadIdx.x;
  int stride = gridDim.x * blockDim.x;
  for (; i < n4; i += stride) {
    float4 v = ((const float4*)src)[i];
    ushort4 o;
    o.x = f2bf(v.x); o.y = f2bf(v.y); o.z = f2bf(v.z); o.w = f2bf(v.w);
    ((ushort4*)dst)[i] = o;
  }
}

// ---- kernel 2/3: transpose-convert W[K][N] f32 -> WT[N][K] bf16 ----------

__global__ __launch_bounds__(256) void k_transpose_cvt(const float* __restrict__ W,
                                                       u16* __restrict__ WT,
                                                       int K, int N) {
  __shared__ float tile[64][65];
  int n0 = blockIdx.x * 64, k0 = blockIdx.y * 64;
  int t = threadIdx.x;
#pragma unroll
  for (int i = 0; i < 16; i++) {
    int idx = i * 256 + t;
    int r = idx >> 6, c = idx & 63;
    tile[r][c] = W[(size_t)(k0 + r) * N + n0 + c];
  }
  __syncthreads();
#pragma unroll
  for (int i = 0; i < 16; i++) {
    int idx = i * 256 + t;
    int r = idx >> 6, c = idx & 63;
    WT[(size_t)(n0 + r) * K + k0 + c] = f2bf(tile[c][r]);
  }
}

// ---- GEMM: C = A @ Bt^T + bias, tile BM x 128, BK=64 (m97 structure) -----

template <int BM, bool OUT_BF16>
__global__ __launch_bounds__(256) void k_gemm_bt(const u16* __restrict__ A,
                                                 const u16* __restrict__ Bt,
                                                 const float* __restrict__ bias,
                                                 void* __restrict__ Cout,
                                                 int M, int N, int K) {
  constexpr int MF = BM / 32;
  __shared__ u16 As[BM * 64];
  __shared__ u16 Bs[128 * 64];
  int t = threadIdx.x;
  int w = t >> 6, l = t & 63;
  int wm = w >> 1, wn = w & 1;
  int m0 = blockIdx.y * BM, n0 = blockIdx.x * 128;

  f32x4 acc[MF][4];
#pragma unroll
  for (int m = 0; m < MF; m++)
#pragma unroll
    for (int n = 0; n < 4; n++) acc[m][n] = (f32x4){0.f, 0.f, 0.f, 0.f};

  int nk = K >> 6;
  for (int kt = 0; kt < nk; kt++) {
#pragma unroll
    for (int i = 0; i < MF; i++) {
      int idx = i * 256 + t;
      int row = idx >> 3, g = idx & 7;
      int gs = g ^ (row & 7);
      gload16(A + (size_t)(m0 + row) * K + kt * 64 + gs * 8, As + idx * 8);
    }
#pragma unroll
    for (int i = 0; i < 4; i++) {
      int idx = i * 256 + t;
      int row = idx >> 3, g = idx & 7;
      int gs = g ^ (row & 7);
      gload16(Bt + (size_t)(n0 + row) * K + kt * 64 + gs * 8, Bs + idx * 8);
    }
    __syncthreads();
#pragma unroll
    for (int kk = 0; kk < 2; kk++) {
      bf16x8 af[MF], bfv[4];
#pragma unroll
      for (int m = 0; m < MF; m++) {
        int row = wm * (BM / 2) + m * 16 + (l & 15);
        int gr = (kk * 4 + (l >> 4)) ^ (row & 7);
        af[m] = *(const bf16x8*)(As + row * 64 + gr * 8);
      }
#pragma unroll
      for (int n = 0; n < 4; n++) {
        int row = wn * 64 + n * 16 + (l & 15);
        int gr = (kk * 4 + (l >> 4)) ^ (row & 7);
        bfv[n] = *(const bf16x8*)(Bs + row * 64 + gr * 8);
      }
#pragma unroll
      for (int m = 0; m < MF; m++)
#pragma unroll
        for (int n = 0; n < 4; n++)
          acc[m][n] = __builtin_amdgcn_mfma_f32_16x16x32_bf16(af[m], bfv[n],
                                                              acc[m][n], 0, 0, 0);
    }
    __syncthreads();
  }

#pragma unroll
  for (int m = 0; m < MF; m++) {
    int row = m0 + wm * (BM / 2) + m * 16 + ((l >> 4) * 4);
#pragma unroll
    for (int n = 0; n < 4; n++) {
      int col = n0 + wn * 64 + n * 16 + (l & 15);
      float bv = bias[col];
#pragma unroll
      for (int r = 0; r < 4; r++) {
        float v = acc[m][n][r] + bv;
        if constexpr (OUT_BF16)
          ((u16*)Cout)[(size_t)(row + r) * N + col] = f2bf(v);
        else
          ((float*)Cout)[(size_t)(row + r) * N + col] = v;
      }
    }
  }
}

// ---- kernel 5: RoPE + RMSNorm + fragment-major repack (q,k only) ---------
// Qf/Kf layout: [bh][T=s/16][kk=d/32][lane][8], lane = ((d>>3)&3)*16 + (s&15).
// q additionally scaled by LOG2E so attn scores arrive in log2 domain.

__global__ __launch_bounds__(256) void k_ropenorm(const u16* __restrict__ qkv,
                                                  const float* __restrict__ wq,
                                                  const float* __restrict__ wk,
                                                  u16* __restrict__ Qf,
                                                  u16* __restrict__ Kf) {
  int wi = blockIdx.x * 4 + (threadIdx.x >> 6);  // (b,h,s)
  int d = threadIdx.x & 63;
  int bh = wi >> 11;
  int s = wi & 2047;
  int b = bh >> 4, h = bh & 15;

  size_t base = (size_t)(b * 2048 + s) * 3072 + h * 64 + d;
  float qv = bf2f(qkv[base]);
  float kv = bf2f(qkv[base + 1024]);

  float invf = exp2f(-13.2877123795449f * (float)(d & 31) * 0.03125f);
  float rev = (float)s * (invf * 0.15915494309189535f);
  float fr = rev - floorf(rev);
  float ang = fr * 6.283185307179586f;
  float sn = __sinf(ang);
  float c = __cosf(ang);

  float qp = __shfl_xor(qv, 32);
  float kp = __shfl_xor(kv, 32);
  float qrot = (d < 32) ? -qp : qp;
  float krot = (d < 32) ? -kp : kp;
  float qr = qv * c + qrot * sn;
  float kr = kv * c + krot * sn;

  float sq = qr * qr, sk = kr * kr;
#pragma unroll
  for (int off = 32; off > 0; off >>= 1) {
    sq += __shfl_xor(sq, off);
    sk += __shfl_xor(sk, off);
  }
  float qn = qr / (sqrtf(sq) * 0.125f + 1e-6f) * wq[d] * (0.125f * LOG2E);
  float kn = kr / (sqrtf(sk) * 0.125f + 1e-6f) * wk[d];

  int T = s >> 4, r = s & 15;
  int kk = d >> 5, sub = (d >> 3) & 3, j = d & 7;
  size_t fi = ((((size_t)bh * 128 + T) * 2 + kk) * 64 + sub * 16 + r) * 8 + j;
  Qf[fi] = f2bf(qn);
  Kf[fi] = f2bf(kn);
}

// ---- kernel 5b: pack V into PV-B-fragment-major layout -------------------
// Vf [bh][st=kv/32][dt=d/16][lane=g*16+lr][8]:
//   elem j<4: kv = st*32 + g*4 + j ; j>=4: kv = st*32 + 16 + g*4 + (j-4); d = dt*16+lr

__global__ __launch_bounds__(256) void k_pack_v(const u16* __restrict__ qkvb,
                                                u16* __restrict__ Vf) {
  __shared__ u16 tile[64][65];
  int s0 = blockIdx.x * 64;
  int bh = blockIdx.y;
  int b = bh >> 4, h = bh & 15;
  int t = threadIdx.x;
#pragma unroll
  for (int i = 0; i < 16; i++) {
    int idx = i * 256 + t;
    int sr = idx >> 6, dc = idx & 63;
    tile[sr][dc] = qkvb[(size_t)(b * 2048 + s0 + sr) * 3072 + 2048 + h * 64 + dc];
  }
  __syncthreads();
#pragma unroll
  for (int i = 0; i < 2; i++) {
    int u = i * 256 + t;
    int stl = u >> 8;
    int rem = u & 255;
    int dt = rem >> 6;
    int lane = rem & 63;
    int g = lane >> 4, lr = lane & 15;
    int d = dt * 16 + lr;
    union { bf16x8 v; u16 h[8]; } o;
#pragma unroll
    for (int j = 0; j < 4; j++) {
      o.h[j]     = tile[stl * 32 + g * 4 + j][d];
      o.h[4 + j] = tile[stl * 32 + 16 + g * 4 + j][d];
    }
    int st = blockIdx.x * 2 + stl;
    *(bf16x8*)(Vf + ((((size_t)bh * 64 + st) * 4 + dt) * 64 + lane) * 8) = o.v;
  }
}

// ---- kernel 6: attention (R18 structure) + Q-reload, 4 blocks/CU ---------
// SINGLE MECHANISM CHANGE vs R18: Q fragments are re-loaded from global per
// (kt, m) instead of held in qf[4][2] (32 VGPR) for the kernel lifetime.
// The 8KB Q tile is L1-resident, so reloads are ~L1-hit latency hidden
// under MFMAs; freed registers + __launch_bounds__(256,4) target 4 blocks/CU
// (was 3). Block-level phase stagger is the only lever that has moved this
// kernel (R13->R15: 2->3 blocks/CU = -11 us); this pushes it to 4.
// LDS 34.3KB x 4 = 137KB < 160 OK.
// grid (B*H, S/64) bh-fastest (XCD pin). 4 waves; wave w owns kv
// [w*512,+512) exclusive. Swapped QK^T: lane holds q=l&15, kv=(l>>4)*4+r.

__global__ __launch_bounds__(256, 4) void k_attn(const u16* __restrict__ Qf,
                                                 const u16* __restrict__ Kf,
                                                 const u16* __restrict__ Vf,
                                                 float* __restrict__ wout,
                                                 u16* __restrict__ aout) {
  __shared__ float red[4][4][16];
  __shared__ float Ored[2][64][65];
  int t = threadIdx.x, w = t >> 6, l = t & 63;
  int g = l >> 4, lr = l & 15;
  int bh = blockIdx.x;        // XCD-pinned: xcd = bh % 8
  int qb = blockIdx.y;
  int q0 = qb * 64;

  const u16* Qbase = Qf + (((size_t)bh * 128 + qb * 4) * 2) * 64 * 8;
  const u16* Kbh = Kf + (size_t)bh * 128 * 2 * 64 * 8;
  const u16* Vbh = Vf + (size_t)bh * 64 * 4 * 64 * 8;

  // ---- pass 1: row sums of exp2(scores) over this wave's kv range ----
  float ls[4] = {0.f, 0.f, 0.f, 0.f};
  for (int kt = 0; kt < 16; kt++) {
    int TA = w * 32 + kt * 2;
    bf16x8 kf[2][2];
#pragma unroll
    for (int tile = 0; tile < 2; tile++)
#pragma unroll
      for (int kk = 0; kk < 2; kk++)
        kf[tile][kk] = *(const bf16x8*)(Kbh + ((((size_t)TA + tile) * 2 + kk) * 64 + l) * 8);
#pragma unroll
    for (int m = 0; m < 4; m++) {
      bf16x8 q0v = *(const bf16x8*)(Qbase + (((size_t)m * 2 + 0) * 64 + l) * 8);
      bf16x8 q1v = *(const bf16x8*)(Qbase + (((size_t)m * 2 + 1) * 64 + l) * 8);
      f32x4 s0 = (f32x4){0.f, 0.f, 0.f, 0.f};
      f32x4 s1 = (f32x4){0.f, 0.f, 0.f, 0.f};
      s0 = __builtin_amdgcn_mfma_f32_16x16x32_bf16(kf[0][0], q0v, s0, 0, 0, 0);
      s1 = __builtin_amdgcn_mfma_f32_16x16x32_bf16(kf[1][0], q0v, s1, 0, 0, 0);
      s0 = __builtin_amdgcn_mfma_f32_16x16x32_bf16(kf[0][1], q1v, s0, 0, 0, 0);
      s1 = __builtin_amdgcn_mfma_f32_16x16x32_bf16(kf[1][1], q1v, s1, 0, 0, 0);
#pragma unroll
      for (int r = 0; r < 4; r++) ls[m] += exp2f(s0[r]) + exp2f(s1[r]);
    }
  }
#pragma unroll
  for (int m = 0; m < 4; m++) {
    ls[m] += __shfl_xor(ls[m], 16);
    ls[m] += __shfl_xor(ls[m], 32);
  }
  if (l < 16)
#pragma unroll
    for (int m = 0; m < 4; m++) red[w][m][l] = ls[m];
  __syncthreads();
  float linv[4];
#pragma unroll
  for (int m = 0; m < 4; m++)
    linv[m] = 1.f / (red[0][m][lr] + red[1][m][lr] + red[2][m][lr] + red[3][m][lr]);

  // ---- pass 2: normalized weights streamed to d_out, PV accumulate ----
  f32x4 oacc[4][4];
#pragma unroll
  for (int m = 0; m < 4; m++)
#pragma unroll
    for (int nf = 0; nf < 4; nf++) oacc[m][nf] = (f32x4){0.f, 0.f, 0.f, 0.f};

  for (int kt = 0; kt < 16; kt++) {
    int TA = w * 32 + kt * 2;
    int st = w * 16 + kt;
    bf16x8 kf[2][2];
#pragma unroll
    for (int tile = 0; tile < 2; tile++)
#pragma unroll
      for (int kk = 0; kk < 2; kk++)
        kf[tile][kk] = *(const bf16x8*)(Kbh + ((((size_t)TA + tile) * 2 + kk) * 64 + l) * 8);
    bf16x8 vf[4];
#pragma unroll
    for (int nf = 0; nf < 4; nf++)
      vf[nf] = *(const bf16x8*)(Vbh + (((size_t)st * 4 + nf) * 64 + l) * 8);

#pragma unroll
    for (int m = 0; m < 4; m++) {
      bf16x8 q0v = *(const bf16x8*)(Qbase + (((size_t)m * 2 + 0) * 64 + l) * 8);
      bf16x8 q1v = *(const bf16x8*)(Qbase + (((size_t)m * 2 + 1) * 64 + l) * 8);
      f32x4 s0 = (f32x4){0.f, 0.f, 0.f, 0.f};
      f32x4 s1 = (f32x4){0.f, 0.f, 0.f, 0.f};
      s0 = __builtin_amdgcn_mfma_f32_16x16x32_bf16(kf[0][0], q0v, s0, 0, 0, 0);
      s1 = __builtin_amdgcn_mfma_f32_16x16x32_bf16(kf[1][0], q0v, s1, 0, 0, 0);
      s0 = __builtin_amdgcn_mfma_f32_16x16x32_bf16(kf[0][1], q1v, s0, 0, 0, 0);
      s1 = __builtin_amdgcn_mfma_f32_16x16x32_bf16(kf[1][1], q1v, s1, 0, 0, 0);
      f32x4 wA, wB;
      bf16x8 pp;
#pragma unroll
      for (int r = 0; r < 4; r++) {
        float pA = exp2f(s0[r]) * linv[m];
        float pB = exp2f(s1[r]) * linv[m];
        wA[r] = pA;
        wB[r] = pB;
        pp[r] = (__bf16)pA;
        pp[4 + r] = (__bf16)pB;
      }
      // one full 128B L2 line per (row, kt): cols [w*512+kt*32, +32)
      size_t wbase = ((size_t)bh * 2048 + q0 + m * 16 + lr) * 2048 + TA * 16 + g * 4;
      *(f32x4*)(wout + wbase) = wA;
      *(f32x4*)(wout + wbase + 16) = wB;
#pragma unroll
      for (int nf = 0; nf < 4; nf++)
        oacc[m][nf] = __builtin_amdgcn_mfma_f32_16x16x32_bf16(pp, vf[nf],
                                                              oacc[m][nf], 0, 0, 0);
    }
  }

  // ---- cross-wave O reduction (already normalized) ----
  if (w >= 2) {
#pragma unroll
    for (int m = 0; m < 4; m++)
#pragma unroll
      for (int nf = 0; nf < 4; nf++)
#pragma unroll
        for (int r = 0; r < 4; r++)
          Ored[w - 2][m * 16 + g * 4 + r][nf * 16 + lr] = oacc[m][nf][r];
  }
  __syncthreads();
  if (w < 2) {
#pragma unroll
    for (int m = 0; m < 4; m++)
#pragma unroll
      for (int nf = 0; nf < 4; nf++)
#pragma unroll
        for (int r = 0; r < 4; r++)
          Ored[w][m * 16 + g * 4 + r][nf * 16 + lr] += oacc[m][nf][r];
  }
  __syncthreads();

  // epilogue: wave w writes q-rows [w*16, w*16+16); lane = d
  int b = bh >> 4, h = bh & 15;
#pragma unroll
  for (int i = 0; i < 16; i++) {
    int q = w * 16 + i;
    float v = Ored[0][q][l] + Ored[1][q][l];
    aout[(size_t)(b * 2048 + q0 + q) * 1024 + h * 64 + l] = f2bf(v);
  }
}

// ---- host ------------------------------------------------------------------

extern "C" void kernel_launch(void* const* d_in, const int* in_sizes, int n_in,
                              void* d_out, int out_size, void* d_ws, size_t ws_size,
                              hipStream_t stream) {
  const float* x     = (const float*)d_in[0];
  const float* Wqkv  = (const float*)d_in[1];
  const float* bqkv  = (const float*)d_in[2];
  const float* Wproj = (const float*)d_in[3];
  const float* bproj = (const float*)d_in[4];
  const float* wq    = (const float*)d_in[5];
  const float* wk    = (const float*)d_in[6];

  float* out  = (float*)d_out;
  float* wout = out + 4194304;

  char* ws = (char*)d_ws;
  u16* xbf    = (u16*)(ws);                          // 8 MB (reused as aout)
  u16* wqkvT  = (u16*)(ws + (size_t)8  * 1048576);   // 6 MB
  u16* wprojT = (u16*)(ws + (size_t)14 * 1048576);   // 2 MB
  u16* qkvb   = (u16*)(ws + (size_t)16 * 1048576);   // 24 MB
  u16* Qfp    = (u16*)(ws + (size_t)40 * 1048576);   // 8 MB fragment-major
  u16* Kfp    = (u16*)(ws + (size_t)48 * 1048576);   // 8 MB fragment-major
  u16* Vfp    = (u16*)(ws + (size_t)56 * 1048576);   // 8 MB fragment-major
  u16* aout   = xbf;

  k_cvt_x<<<2048, 256, 0, stream>>>(x, xbf, 4194304 / 4);
  k_transpose_cvt<<<dim3(48, 16), 256, 0, stream>>>(Wqkv, wqkvT, 1024, 3072);
  k_transpose_cvt<<<dim3(16, 16), 256, 0, stream>>>(Wproj, wprojT, 1024, 1024);

  k_gemm_bt<128, true><<<dim3(24, 32), 256, 0, stream>>>(xbf, wqkvT, bqkv, qkvb,
                                                         4096, 3072, 1024);
  k_ropenorm<<<16384, 256, 0, stream>>>(qkvb, wq, wk, Qfp, Kfp);
  k_pack_v<<<dim3(32, 32), 256, 0, stream>>>(qkvb, Vfp);
  // R18 attention + Q-reload-from-L1 + __launch_bounds__(256,4)
  k_attn<<<dim3(32, 32), 256, 0, stream>>>(Qfp, Kfp, Vfp, wout, aout);
  // BM=64: 512 blocks = 2/CU
  k_gemm_bt<64, false><<<dim3(8, 64), 256, 0, stream>>>(aout, wprojT, bproj, out,
                                                        4096, 1024, 1024);
}

// Round 21
// 226.985 us; speedup vs baseline: 1.4869x; 1.4869x over previous
//
#include <hip/hip_runtime.h>

typedef unsigned short u16;
typedef __bf16 bf16x8 __attribute__((ext_vector_type(8)));
typedef float f32x4 __attribute__((ext_vector_type(4)));

#define LOG2E 1.44269504088896f

// ---- helpers -------------------------------------------------------------

__device__ __forceinline__ u16 f2bf(float f) {
  unsigned u = __float_as_uint(f);
  u += 0x7fffu + ((u >> 16) & 1u);   // RNE
  return (u16)(u >> 16);
}
__device__ __forceinline__ float bf2f(u16 h) {
  return __uint_as_float(((unsigned)h) << 16);
}

__device__ __forceinline__ void gload16(const void* g, void* l) {
  __builtin_amdgcn_global_load_lds(
      (const __attribute__((address_space(1))) unsigned int*)g,
      (__attribute__((address_space(3))) unsigned int*)l, 16, 0, 0);
}

// ---- kernel 1: f32 -> bf16 copy ------------------------------------------

__global__ __launch_bounds__(256) void k_cvt_x(const float* __restrict__ src,
                                               u16* __restrict__ dst, int n4) {
  int i = blockIdx.x * blockDim.x + threadIdx.x;
  int stride = gridDim.x * blockDim.x;
  for (; i < n4; i += stride) {
    float4 v = ((const float4*)src)[i];
    ushort4 o;
    o.x = f2bf(v.x); o.y = f2bf(v.y); o.z = f2bf(v.z); o.w = f2bf(v.w);
    ((ushort4*)dst)[i] = o;
  }
}

// ---- kernel 2/3: transpose-convert W[K][N] f32 -> WT[N][K] bf16 ----------

__global__ __launch_bounds__(256) void k_transpose_cvt(const float* __restrict__ W,
                                                       u16* __restrict__ WT,
                                                       int K, int N) {
  __shared__ float tile[64][65];
  int n0 = blockIdx.x * 64, k0 = blockIdx.y * 64;
  int t = threadIdx.x;
#pragma unroll
  for (int i = 0; i < 16; i++) {
    int idx = i * 256 + t;
    int r = idx >> 6, c = idx & 63;
    tile[r][c] = W[(size_t)(k0 + r) * N + n0 + c];
  }
  __syncthreads();
#pragma unroll
  for (int i = 0; i < 16; i++) {
    int idx = i * 256 + t;
    int r = idx >> 6, c = idx & 63;
    WT[(size_t)(n0 + r) * K + k0 + c] = f2bf(tile[c][r]);
  }
}

// ---- GEMM: C = A @ Bt^T + bias, tile BM x 128, BK=64 (m97 structure) -----

template <int BM, bool OUT_BF16>
__global__ __launch_bounds__(256) void k_gemm_bt(const u16* __restrict__ A,
                                                 const u16* __restrict__ Bt,
                                                 const float* __restrict__ bias,
                                                 void* __restrict__ Cout,
                                                 int M, int N, int K) {
  constexpr int MF = BM / 32;
  __shared__ u16 As[BM * 64];
  __shared__ u16 Bs[128 * 64];
  int t = threadIdx.x;
  int w = t >> 6, l = t & 63;
  int wm = w >> 1, wn = w & 1;
  int m0 = blockIdx.y * BM, n0 = blockIdx.x * 128;

  f32x4 acc[MF][4];
#pragma unroll
  for (int m = 0; m < MF; m++)
#pragma unroll
    for (int n = 0; n < 4; n++) acc[m][n] = (f32x4){0.f, 0.f, 0.f, 0.f};

  int nk = K >> 6;
  for (int kt = 0; kt < nk; kt++) {
#pragma unroll
    for (int i = 0; i < MF; i++) {
      int idx = i * 256 + t;
      int row = idx >> 3, g = idx & 7;
      int gs = g ^ (row & 7);
      gload16(A + (size_t)(m0 + row) * K + kt * 64 + gs * 8, As + idx * 8);
    }
#pragma unroll
    for (int i = 0; i < 4; i++) {
      int idx = i * 256 + t;
      int row = idx >> 3, g = idx & 7;
      int gs = g ^ (row & 7);
      gload16(Bt + (size_t)(n0 + row) * K + kt * 64 + gs * 8, Bs + idx * 8);
    }
    __syncthreads();
#pragma unroll
    for (int kk = 0; kk < 2; kk++) {
      bf16x8 af[MF], bfv[4];
#pragma unroll
      for (int m = 0; m < MF; m++) {
        int row = wm * (BM / 2) + m * 16 + (l & 15);
        int gr = (kk * 4 + (l >> 4)) ^ (row & 7);
        af[m] = *(const bf16x8*)(As + row * 64 + gr * 8);
      }
#pragma unroll
      for (int n = 0; n < 4; n++) {
        int row = wn * 64 + n * 16 + (l & 15);
        int gr = (kk * 4 + (l >> 4)) ^ (row & 7);
        bfv[n] = *(const bf16x8*)(Bs + row * 64 + gr * 8);
      }
#pragma unroll
      for (int m = 0; m < MF; m++)
#pragma unroll
        for (int n = 0; n < 4; n++)
          acc[m][n] = __builtin_amdgcn_mfma_f32_16x16x32_bf16(af[m], bfv[n],
                                                              acc[m][n], 0, 0, 0);
    }
    __syncthreads();
  }

#pragma unroll
  for (int m = 0; m < MF; m++) {
    int row = m0 + wm * (BM / 2) + m * 16 + ((l >> 4) * 4);
#pragma unroll
    for (int n = 0; n < 4; n++) {
      int col = n0 + wn * 64 + n * 16 + (l & 15);
      float bv = bias[col];
#pragma unroll
      for (int r = 0; r < 4; r++) {
        float v = acc[m][n][r] + bv;
        if constexpr (OUT_BF16)
          ((u16*)Cout)[(size_t)(row + r) * N + col] = f2bf(v);
        else
          ((float*)Cout)[(size_t)(row + r) * N + col] = v;
      }
    }
  }
}

// ---- kernel 5: RoPE + RMSNorm + fragment-major repack (q,k only) ---------
// Qf/Kf layout: [bh][T=s/16][kk=d/32][lane][8], lane = ((d>>3)&3)*16 + (s&15).
// q additionally scaled by LOG2E so attn scores arrive in log2 domain.

__global__ __launch_bounds__(256) void k_ropenorm(const u16* __restrict__ qkv,
                                                  const float* __restrict__ wq,
                                                  const float* __restrict__ wk,
                                                  u16* __restrict__ Qf,
                                                  u16* __restrict__ Kf) {
  int wi = blockIdx.x * 4 + (threadIdx.x >> 6);  // (b,h,s)
  int d = threadIdx.x & 63;
  int bh = wi >> 11;
  int s = wi & 2047;
  int b = bh >> 4, h = bh & 15;

  size_t base = (size_t)(b * 2048 + s) * 3072 + h * 64 + d;
  float qv = bf2f(qkv[base]);
  float kv = bf2f(qkv[base + 1024]);

  float invf = exp2f(-13.2877123795449f * (float)(d & 31) * 0.03125f);
  float rev = (float)s * (invf * 0.15915494309189535f);
  float fr = rev - floorf(rev);
  float ang = fr * 6.283185307179586f;
  float sn = __sinf(ang);
  float c = __cosf(ang);

  float qp = __shfl_xor(qv, 32);
  float kp = __shfl_xor(kv, 32);
  float qrot = (d < 32) ? -qp : qp;
  float krot = (d < 32) ? -kp : kp;
  float qr = qv * c + qrot * sn;
  float kr = kv * c + krot * sn;

  float sq = qr * qr, sk = kr * kr;
#pragma unroll
  for (int off = 32; off > 0; off >>= 1) {
    sq += __shfl_xor(sq, off);
    sk += __shfl_xor(sk, off);
  }
  float qn = qr / (sqrtf(sq) * 0.125f + 1e-6f) * wq[d] * (0.125f * LOG2E);
  float kn = kr / (sqrtf(sk) * 0.125f + 1e-6f) * wk[d];

  int T = s >> 4, r = s & 15;
  int kk = d >> 5, sub = (d >> 3) & 3, j = d & 7;
  size_t fi = ((((size_t)bh * 128 + T) * 2 + kk) * 64 + sub * 16 + r) * 8 + j;
  Qf[fi] = f2bf(qn);
  Kf[fi] = f2bf(kn);
}

// ---- kernel 5b: pack V into PV-B-fragment-major layout -------------------
// Vf [bh][st=kv/32][dt=d/16][lane=g*16+lr][8]:
//   elem j<4: kv = st*32 + g*4 + j ; j>=4: kv = st*32 + 16 + g*4 + (j-4); d = dt*16+lr

__global__ __launch_bounds__(256) void k_pack_v(const u16* __restrict__ qkvb,
                                                u16* __restrict__ Vf) {
  __shared__ u16 tile[64][65];
  int s0 = blockIdx.x * 64;
  int bh = blockIdx.y;
  int b = bh >> 4, h = bh & 15;
  int t = threadIdx.x;
#pragma unroll
  for (int i = 0; i < 16; i++) {
    int idx = i * 256 + t;
    int sr = idx >> 6, dc = idx & 63;
    tile[sr][dc] = qkvb[(size_t)(b * 2048 + s0 + sr) * 3072 + 2048 + h * 64 + dc];
  }
  __syncthreads();
#pragma unroll
  for (int i = 0; i < 2; i++) {
    int u = i * 256 + t;
    int stl = u >> 8;
    int rem = u & 255;
    int dt = rem >> 6;
    int lane = rem & 63;
    int g = lane >> 4, lr = lane & 15;
    int d = dt * 16 + lr;
    union { bf16x8 v; u16 h[8]; } o;
#pragma unroll
    for (int j = 0; j < 4; j++) {
      o.h[j]     = tile[stl * 32 + g * 4 + j][d];
      o.h[4 + j] = tile[stl * 32 + 16 + g * 4 + j][d];
    }
    int st = blockIdx.x * 2 + stl;
    *(bf16x8*)(Vf + ((((size_t)bh * 64 + st) * 4 + dt) * 64 + lane) * 8) = o.v;
  }
}

// ---- kernel 6: attention (R18 config — measured best, 227.7 µs) ----------
// R15 structure + __launch_bounds__(256, 3). Two-pass 64q, XCD-pinned,
// exclusive contiguous kv per wave, streamed normalized stores, per-m
// low-register inner loops. All five perturbations (fat blocks, nt stores,
// load prefetch, Q-reload, 4-block cap) regressed; this is the plateau.
// grid (B*H, S/64) bh-fastest (XCD pin). 4 waves; wave w owns kv
// [w*512, w*512+512) exclusive. Swapped QK^T: lane holds q=l&15,
// kv=(l>>4)*4+r. Scores in log2 domain (q pre-scaled by LOG2E).

__global__ __launch_bounds__(256, 3) void k_attn(const u16* __restrict__ Qf,
                                                 const u16* __restrict__ Kf,
                                                 const u16* __restrict__ Vf,
                                                 float* __restrict__ wout,
                                                 u16* __restrict__ aout) {
  __shared__ float red[4][4][16];
  __shared__ float Ored[2][64][65];
  int t = threadIdx.x, w = t >> 6, l = t & 63;
  int g = l >> 4, lr = l & 15;
  int bh = blockIdx.x;        // XCD-pinned: xcd = bh % 8
  int qb = blockIdx.y;
  int q0 = qb * 64;

  const u16* Qbase = Qf + (((size_t)bh * 128 + qb * 4) * 2) * 64 * 8;
  const u16* Kbh = Kf + (size_t)bh * 128 * 2 * 64 * 8;
  const u16* Vbh = Vf + (size_t)bh * 64 * 4 * 64 * 8;

  bf16x8 qf[4][2];
#pragma unroll
  for (int m = 0; m < 4; m++)
#pragma unroll
    for (int kk = 0; kk < 2; kk++)
      qf[m][kk] = *(const bf16x8*)(Qbase + (((size_t)m * 2 + kk) * 64 + l) * 8);

  // ---- pass 1: row sums of exp2(scores) over this wave's kv range ----
  float ls[4] = {0.f, 0.f, 0.f, 0.f};
  for (int kt = 0; kt < 16; kt++) {
    int TA = w * 32 + kt * 2;
    bf16x8 kf[2][2];
#pragma unroll
    for (int tile = 0; tile < 2; tile++)
#pragma unroll
      for (int kk = 0; kk < 2; kk++)
        kf[tile][kk] = *(const bf16x8*)(Kbh + ((((size_t)TA + tile) * 2 + kk) * 64 + l) * 8);
#pragma unroll
    for (int m = 0; m < 4; m++) {
      f32x4 s0 = (f32x4){0.f, 0.f, 0.f, 0.f};
      f32x4 s1 = (f32x4){0.f, 0.f, 0.f, 0.f};
#pragma unroll
      for (int kk = 0; kk < 2; kk++) {
        s0 = __builtin_amdgcn_mfma_f32_16x16x32_bf16(kf[0][kk], qf[m][kk], s0, 0, 0, 0);
        s1 = __builtin_amdgcn_mfma_f32_16x16x32_bf16(kf[1][kk], qf[m][kk], s1, 0, 0, 0);
      }
#pragma unroll
      for (int r = 0; r < 4; r++) ls[m] += exp2f(s0[r]) + exp2f(s1[r]);
    }
  }
#pragma unroll
  for (int m = 0; m < 4; m++) {
    ls[m] += __shfl_xor(ls[m], 16);
    ls[m] += __shfl_xor(ls[m], 32);
  }
  if (l < 16)
#pragma unroll
    for (int m = 0; m < 4; m++) red[w][m][l] = ls[m];
  __syncthreads();
  float linv[4];
#pragma unroll
  for (int m = 0; m < 4; m++)
    linv[m] = 1.f / (red[0][m][lr] + red[1][m][lr] + red[2][m][lr] + red[3][m][lr]);

  // ---- pass 2: normalized weights streamed to d_out, PV accumulate ----
  f32x4 oacc[4][4];
#pragma unroll
  for (int m = 0; m < 4; m++)
#pragma unroll
    for (int nf = 0; nf < 4; nf++) oacc[m][nf] = (f32x4){0.f, 0.f, 0.f, 0.f};

  for (int kt = 0; kt < 16; kt++) {
    int TA = w * 32 + kt * 2;
    int st = w * 16 + kt;
    bf16x8 kf[2][2];
#pragma unroll
    for (int tile = 0; tile < 2; tile++)
#pragma unroll
      for (int kk = 0; kk < 2; kk++)
        kf[tile][kk] = *(const bf16x8*)(Kbh + ((((size_t)TA + tile) * 2 + kk) * 64 + l) * 8);
    bf16x8 vf[4];
#pragma unroll
    for (int nf = 0; nf < 4; nf++)
      vf[nf] = *(const bf16x8*)(Vbh + (((size_t)st * 4 + nf) * 64 + l) * 8);

#pragma unroll
    for (int m = 0; m < 4; m++) {
      f32x4 s0 = (f32x4){0.f, 0.f, 0.f, 0.f};
      f32x4 s1 = (f32x4){0.f, 0.f, 0.f, 0.f};
#pragma unroll
      for (int kk = 0; kk < 2; kk++) {
        s0 = __builtin_amdgcn_mfma_f32_16x16x32_bf16(kf[0][kk], qf[m][kk], s0, 0, 0, 0);
        s1 = __builtin_amdgcn_mfma_f32_16x16x32_bf16(kf[1][kk], qf[m][kk], s1, 0, 0, 0);
      }
      f32x4 wA, wB;
      bf16x8 pp;
#pragma unroll
      for (int r = 0; r < 4; r++) {
        float pA = exp2f(s0[r]) * linv[m];
        float pB = exp2f(s1[r]) * linv[m];
        wA[r] = pA;
        wB[r] = pB;
        pp[r] = (__bf16)pA;
        pp[4 + r] = (__bf16)pB;
      }
      // one full 128B L2 line per (row, kt): cols [w*512+kt*32, +32)
      size_t wbase = ((size_t)bh * 2048 + q0 + m * 16 + lr) * 2048 + TA * 16 + g * 4;
      *(f32x4*)(wout + wbase) = wA;
      *(f32x4*)(wout + wbase + 16) = wB;
#pragma unroll
      for (int nf = 0; nf < 4; nf++)
        oacc[m][nf] = __builtin_amdgcn_mfma_f32_16x16x32_bf16(pp, vf[nf],
                                                              oacc[m][nf], 0, 0, 0);
    }
  }

  // ---- cross-wave O reduction (already normalized) ----
  if (w >= 2) {
#pragma unroll
    for (int m = 0; m < 4; m++)
#pragma unroll
      for (int nf = 0; nf < 4; nf++)
#pragma unroll
        for (int r = 0; r < 4; r++)
          Ored[w - 2][m * 16 + g * 4 + r][nf * 16 + lr] = oacc[m][nf][r];
  }
  __syncthreads();
  if (w < 2) {
#pragma unroll
    for (int m = 0; m < 4; m++)
#pragma unroll
      for (int nf = 0; nf < 4; nf++)
#pragma unroll
        for (int r = 0; r < 4; r++)
          Ored[w][m * 16 + g * 4 + r][nf * 16 + lr] += oacc[m][nf][r];
  }
  __syncthreads();

  // epilogue: wave w writes q-rows [w*16, w*16+16); lane = d
  int b = bh >> 4, h = bh & 15;
#pragma unroll
  for (int i = 0; i < 16; i++) {
    int q = w * 16 + i;
    float v = Ored[0][q][l] + Ored[1][q][l];
    aout[(size_t)(b * 2048 + q0 + q) * 1024 + h * 64 + l] = f2bf(v);
  }
}

// ---- host ------------------------------------------------------------------

extern "C" void kernel_launch(void* const* d_in, const int* in_sizes, int n_in,
                              void* d_out, int out_size, void* d_ws, size_t ws_size,
                              hipStream_t stream) {
  const float* x     = (const float*)d_in[0];
  const float* Wqkv  = (const float*)d_in[1];
  const float* bqkv  = (const float*)d_in[2];
  const float* Wproj = (const float*)d_in[3];
  const float* bproj = (const float*)d_in[4];
  const float* wq    = (const float*)d_in[5];
  const float* wk    = (const float*)d_in[6];

  float* out  = (float*)d_out;
  float* wout = out + 4194304;

  char* ws = (char*)d_ws;
  u16* xbf    = (u16*)(ws);                          // 8 MB (reused as aout)
  u16* wqkvT  = (u16*)(ws + (size_t)8  * 1048576);   // 6 MB
  u16* wprojT = (u16*)(ws + (size_t)14 * 1048576);   // 2 MB
  u16* qkvb   = (u16*)(ws + (size_t)16 * 1048576);   // 24 MB
  u16* Qfp    = (u16*)(ws + (size_t)40 * 1048576);   // 8 MB fragment-major
  u16* Kfp    = (u16*)(ws + (size_t)48 * 1048576);   // 8 MB fragment-major
  u16* Vfp    = (u16*)(ws + (size_t)56 * 1048576);   // 8 MB fragment-major
  u16* aout   = xbf;

  k_cvt_x<<<2048, 256, 0, stream>>>(x, xbf, 4194304 / 4);
  k_transpose_cvt<<<dim3(48, 16), 256, 0, stream>>>(Wqkv, wqkvT, 1024, 3072);
  k_transpose_cvt<<<dim3(16, 16), 256, 0, stream>>>(Wproj, wprojT, 1024, 1024);

  k_gemm_bt<128, true><<<dim3(24, 32), 256, 0, stream>>>(xbf, wqkvT, bqkv, qkvb,
                                                         4096, 3072, 1024);
  k_ropenorm<<<16384, 256, 0, stream>>>(qkvb, wq, wk, Qfp, Kfp);
  k_pack_v<<<dim3(32, 32), 256, 0, stream>>>(qkvb, Vfp);
  // R18 attention: R15 structure + __launch_bounds__(256,3) — measured best
  k_attn<<<dim3(32, 32), 256, 0, stream>>>(Qfp, Kfp, Vfp, wout, aout);
  // BM=64: 512 blocks = 2/CU
  k_gemm_bt<64, false><<<dim3(8, 64), 256, 0, stream>>>(aout, wprojT, bproj, out,
                                                        4096, 1024, 1024);
}

// Round 22
// 226.339 us; speedup vs baseline: 1.4911x; 1.0029x over previous
//
#include <hip/hip_runtime.h>

typedef unsigned short u16;
typedef __bf16 bf16x8 __attribute__((ext_vector_type(8)));
typedef float f32x4 __attribute__((ext_vector_type(4)));

#define LOG2E 1.44269504088896f

// ---- helpers -------------------------------------------------------------

__device__ __forceinline__ u16 f2bf(float f) {
  unsigned u = __float_as_uint(f);
  u += 0x7fffu + ((u >> 16) & 1u);   // RNE
  return (u16)(u >> 16);
}
__device__ __forceinline__ float bf2f(u16 h) {
  return __uint_as_float(((unsigned)h) << 16);
}

__device__ __forceinline__ void gload16(const void* g, void* l) {
  __builtin_amdgcn_global_load_lds(
      (const __attribute__((address_space(1))) unsigned int*)g,
      (__attribute__((address_space(3))) unsigned int*)l, 16, 0, 0);
}

// ---- kernel 1: f32 -> bf16 copy ------------------------------------------

__global__ __launch_bounds__(256) void k_cvt_x(const float* __restrict__ src,
                                               u16* __restrict__ dst, int n4) {
  int i = blockIdx.x * blockDim.x + threadIdx.x;
  int stride = gridDim.x * blockDim.x;
  for (; i < n4; i += stride) {
    float4 v = ((const float4*)src)[i];
    ushort4 o;
    o.x = f2bf(v.x); o.y = f2bf(v.y); o.z = f2bf(v.z); o.w = f2bf(v.w);
    ((ushort4*)dst)[i] = o;
  }
}

// ---- kernel 2/3: transpose-convert W[K][N] f32 -> WT[N][K] bf16 ----------

__global__ __launch_bounds__(256) void k_transpose_cvt(const float* __restrict__ W,
                                                       u16* __restrict__ WT,
                                                       int K, int N) {
  __shared__ float tile[64][65];
  int n0 = blockIdx.x * 64, k0 = blockIdx.y * 64;
  int t = threadIdx.x;
#pragma unroll
  for (int i = 0; i < 16; i++) {
    int idx = i * 256 + t;
    int r = idx >> 6, c = idx & 63;
    tile[r][c] = W[(size_t)(k0 + r) * N + n0 + c];
  }
  __syncthreads();
#pragma unroll
  for (int i = 0; i < 16; i++) {
    int idx = i * 256 + t;
    int r = idx >> 6, c = idx & 63;
    WT[(size_t)(n0 + r) * K + k0 + c] = f2bf(tile[c][r]);
  }
}

// ---- GEMM: C = A @ Bt^T + bias, tile BM x 128, BK=64 (m97 structure) -----
// NEW vs R21: bijective XCD-aware block swizzle (T1). Both grids are
// multiples of 8 (768, 512), so swz = (wgid%8)*(nwg/8) + wgid/8 gives each
// XCD a CONTIGUOUS range of tiles: 4+ consecutive by-rows share A panels
// and walk B panels sequentially -> panel re-reads become per-XCD L2 hits
// instead of HBM/L3 round trips.

template <int BM, bool OUT_BF16>
__global__ __launch_bounds__(256) void k_gemm_bt(const u16* __restrict__ A,
                                                 const u16* __restrict__ Bt,
                                                 const float* __restrict__ bias,
                                                 void* __restrict__ Cout,
                                                 int M, int N, int K) {
  constexpr int MF = BM / 32;
  __shared__ u16 As[BM * 64];
  __shared__ u16 Bs[128 * 64];
  int t = threadIdx.x;
  int w = t >> 6, l = t & 63;
  int wm = w >> 1, wn = w & 1;

  // XCD swizzle (bijective: gridDim.x*gridDim.y % 8 == 0 for both GEMMs)
  int nbx = gridDim.x;
  int nwg = nbx * gridDim.y;
  int wgid = blockIdx.y * nbx + blockIdx.x;
  int cpx = nwg >> 3;
  int swz = (wgid & 7) * cpx + (wgid >> 3);
  int bx = swz % nbx, by = swz / nbx;

  int m0 = by * BM, n0 = bx * 128;

  f32x4 acc[MF][4];
#pragma unroll
  for (int m = 0; m < MF; m++)
#pragma unroll
    for (int n = 0; n < 4; n++) acc[m][n] = (f32x4){0.f, 0.f, 0.f, 0.f};

  int nk = K >> 6;
  for (int kt = 0; kt < nk; kt++) {
#pragma unroll
    for (int i = 0; i < MF; i++) {
      int idx = i * 256 + t;
      int row = idx >> 3, g = idx & 7;
      int gs = g ^ (row & 7);
      gload16(A + (size_t)(m0 + row) * K + kt * 64 + gs * 8, As + idx * 8);
    }
#pragma unroll
    for (int i = 0; i < 4; i++) {
      int idx = i * 256 + t;
      int row = idx >> 3, g = idx & 7;
      int gs = g ^ (row & 7);
      gload16(Bt + (size_t)(n0 + row) * K + kt * 64 + gs * 8, Bs + idx * 8);
    }
    __syncthreads();
#pragma unroll
    for (int kk = 0; kk < 2; kk++) {
      bf16x8 af[MF], bfv[4];
#pragma unroll
      for (int m = 0; m < MF; m++) {
        int row = wm * (BM / 2) + m * 16 + (l & 15);
        int gr = (kk * 4 + (l >> 4)) ^ (row & 7);
        af[m] = *(const bf16x8*)(As + row * 64 + gr * 8);
      }
#pragma unroll
      for (int n = 0; n < 4; n++) {
        int row = wn * 64 + n * 16 + (l & 15);
        int gr = (kk * 4 + (l >> 4)) ^ (row & 7);
        bfv[n] = *(const bf16x8*)(Bs + row * 64 + gr * 8);
      }
#pragma unroll
      for (int m = 0; m < MF; m++)
#pragma unroll
        for (int n = 0; n < 4; n++)
          acc[m][n] = __builtin_amdgcn_mfma_f32_16x16x32_bf16(af[m], bfv[n],
                                                              acc[m][n], 0, 0, 0);
    }
    __syncthreads();
  }

#pragma unroll
  for (int m = 0; m < MF; m++) {
    int row = m0 + wm * (BM / 2) + m * 16 + ((l >> 4) * 4);
#pragma unroll
    for (int n = 0; n < 4; n++) {
      int col = n0 + wn * 64 + n * 16 + (l & 15);
      float bv = bias[col];
#pragma unroll
      for (int r = 0; r < 4; r++) {
        float v = acc[m][n][r] + bv;
        if constexpr (OUT_BF16)
          ((u16*)Cout)[(size_t)(row + r) * N + col] = f2bf(v);
        else
          ((float*)Cout)[(size_t)(row + r) * N + col] = v;
      }
    }
  }
}

// ---- kernel 5: RoPE + RMSNorm + fragment-major repack (q,k only) ---------
// Qf/Kf layout: [bh][T=s/16][kk=d/32][lane][8], lane = ((d>>3)&3)*16 + (s&15).
// q additionally scaled by LOG2E so attn scores arrive in log2 domain.

__global__ __launch_bounds__(256) void k_ropenorm(const u16* __restrict__ qkv,
                                                  const float* __restrict__ wq,
                                                  const float* __restrict__ wk,
                                                  u16* __restrict__ Qf,
                                                  u16* __restrict__ Kf) {
  int wi = blockIdx.x * 4 + (threadIdx.x >> 6);  // (b,h,s)
  int d = threadIdx.x & 63;
  int bh = wi >> 11;
  int s = wi & 2047;
  int b = bh >> 4, h = bh & 15;

  size_t base = (size_t)(b * 2048 + s) * 3072 + h * 64 + d;
  float qv = bf2f(qkv[base]);
  float kv = bf2f(qkv[base + 1024]);

  float invf = exp2f(-13.2877123795449f * (float)(d & 31) * 0.03125f);
  float rev = (float)s * (invf * 0.15915494309189535f);
  float fr = rev - floorf(rev);
  float ang = fr * 6.283185307179586f;
  float sn = __sinf(ang);
  float c = __cosf(ang);

  float qp = __shfl_xor(qv, 32);
  float kp = __shfl_xor(kv, 32);
  float qrot = (d < 32) ? -qp : qp;
  float krot = (d < 32) ? -kp : kp;
  float qr = qv * c + qrot * sn;
  float kr = kv * c + krot * sn;

  float sq = qr * qr, sk = kr * kr;
#pragma unroll
  for (int off = 32; off > 0; off >>= 1) {
    sq += __shfl_xor(sq, off);
    sk += __shfl_xor(sk, off);
  }
  float qn = qr / (sqrtf(sq) * 0.125f + 1e-6f) * wq[d] * (0.125f * LOG2E);
  float kn = kr / (sqrtf(sk) * 0.125f + 1e-6f) * wk[d];

  int T = s >> 4, r = s & 15;
  int kk = d >> 5, sub = (d >> 3) & 3, j = d & 7;
  size_t fi = ((((size_t)bh * 128 + T) * 2 + kk) * 64 + sub * 16 + r) * 8 + j;
  Qf[fi] = f2bf(qn);
  Kf[fi] = f2bf(kn);
}

// ---- kernel 5b: pack V into PV-B-fragment-major layout -------------------
// Vf [bh][st=kv/32][dt=d/16][lane=g*16+lr][8]:
//   elem j<4: kv = st*32 + g*4 + j ; j>=4: kv = st*32 + 16 + g*4 + (j-4); d = dt*16+lr

__global__ __launch_bounds__(256) void k_pack_v(const u16* __restrict__ qkvb,
                                                u16* __restrict__ Vf) {
  __shared__ u16 tile[64][65];
  int s0 = blockIdx.x * 64;
  int bh = blockIdx.y;
  int b = bh >> 4, h = bh & 15;
  int t = threadIdx.x;
#pragma unroll
  for (int i = 0; i < 16; i++) {
    int idx = i * 256 + t;
    int sr = idx >> 6, dc = idx & 63;
    tile[sr][dc] = qkvb[(size_t)(b * 2048 + s0 + sr) * 3072 + 2048 + h * 64 + dc];
  }
  __syncthreads();
#pragma unroll
  for (int i = 0; i < 2; i++) {
    int u = i * 256 + t;
    int stl = u >> 8;
    int rem = u & 255;
    int dt = rem >> 6;
    int lane = rem & 63;
    int g = lane >> 4, lr = lane & 15;
    int d = dt * 16 + lr;
    union { bf16x8 v; u16 h[8]; } o;
#pragma unroll
    for (int j = 0; j < 4; j++) {
      o.h[j]     = tile[stl * 32 + g * 4 + j][d];
      o.h[4 + j] = tile[stl * 32 + 16 + g * 4 + j][d];
    }
    int st = blockIdx.x * 2 + stl;
    *(bf16x8*)(Vf + ((((size_t)bh * 64 + st) * 4 + dt) * 64 + lane) * 8) = o.v;
  }
}

// ---- kernel 6: attention (R18/R21 config — measured best, 227 µs) --------
// Two-pass 64q, XCD-pinned, exclusive contiguous kv per wave, streamed
// normalized stores, per-m low-register inner loops, (256,3) cap.
// grid (B*H, S/64) bh-fastest (XCD pin). 4 waves; wave w owns kv
// [w*512, w*512+512) exclusive. Swapped QK^T: lane holds q=l&15,
// kv=(l>>4)*4+r. Scores in log2 domain (q pre-scaled by LOG2E).

__global__ __launch_bounds__(256, 3) void k_attn(const u16* __restrict__ Qf,
                                                 const u16* __restrict__ Kf,
                                                 const u16* __restrict__ Vf,
                                                 float* __restrict__ wout,
                                                 u16* __restrict__ aout) {
  __shared__ float red[4][4][16];
  __shared__ float Ored[2][64][65];
  int t = threadIdx.x, w = t >> 6, l = t & 63;
  int g = l >> 4, lr = l & 15;
  int bh = blockIdx.x;        // XCD-pinned: xcd = bh % 8
  int qb = blockIdx.y;
  int q0 = qb * 64;

  const u16* Qbase = Qf + (((size_t)bh * 128 + qb * 4) * 2) * 64 * 8;
  const u16* Kbh = Kf + (size_t)bh * 128 * 2 * 64 * 8;
  const u16* Vbh = Vf + (size_t)bh * 64 * 4 * 64 * 8;

  bf16x8 qf[4][2];
#pragma unroll
  for (int m = 0; m < 4; m++)
#pragma unroll
    for (int kk = 0; kk < 2; kk++)
      qf[m][kk] = *(const bf16x8*)(Qbase + (((size_t)m * 2 + kk) * 64 + l) * 8);

  // ---- pass 1: row sums of exp2(scores) over this wave's kv range ----
  float ls[4] = {0.f, 0.f, 0.f, 0.f};
  for (int kt = 0; kt < 16; kt++) {
    int TA = w * 32 + kt * 2;
    bf16x8 kf[2][2];
#pragma unroll
    for (int tile = 0; tile < 2; tile++)
#pragma unroll
      for (int kk = 0; kk < 2; kk++)
        kf[tile][kk] = *(const bf16x8*)(Kbh + ((((size_t)TA + tile) * 2 + kk) * 64 + l) * 8);
#pragma unroll
    for (int m = 0; m < 4; m++) {
      f32x4 s0 = (f32x4){0.f, 0.f, 0.f, 0.f};
      f32x4 s1 = (f32x4){0.f, 0.f, 0.f, 0.f};
#pragma unroll
      for (int kk = 0; kk < 2; kk++) {
        s0 = __builtin_amdgcn_mfma_f32_16x16x32_bf16(kf[0][kk], qf[m][kk], s0, 0, 0, 0);
        s1 = __builtin_amdgcn_mfma_f32_16x16x32_bf16(kf[1][kk], qf[m][kk], s1, 0, 0, 0);
      }
#pragma unroll
      for (int r = 0; r < 4; r++) ls[m] += exp2f(s0[r]) + exp2f(s1[r]);
    }
  }
#pragma unroll
  for (int m = 0; m < 4; m++) {
    ls[m] += __shfl_xor(ls[m], 16);
    ls[m] += __shfl_xor(ls[m], 32);
  }
  if (l < 16)
#pragma unroll
    for (int m = 0; m < 4; m++) red[w][m][l] = ls[m];
  __syncthreads();
  float linv[4];
#pragma unroll
  for (int m = 0; m < 4; m++)
    linv[m] = 1.f / (red[0][m][lr] + red[1][m][lr] + red[2][m][lr] + red[3][m][lr]);

  // ---- pass 2: normalized weights streamed to d_out, PV accumulate ----
  f32x4 oacc[4][4];
#pragma unroll
  for (int m = 0; m < 4; m++)
#pragma unroll
    for (int nf = 0; nf < 4; nf++) oacc[m][nf] = (f32x4){0.f, 0.f, 0.f, 0.f};

  for (int kt = 0; kt < 16; kt++) {
    int TA = w * 32 + kt * 2;
    int st = w * 16 + kt;
    bf16x8 kf[2][2];
#pragma unroll
    for (int tile = 0; tile < 2; tile++)
#pragma unroll
      for (int kk = 0; kk < 2; kk++)
        kf[tile][kk] = *(const bf16x8*)(Kbh + ((((size_t)TA + tile) * 2 + kk) * 64 + l) * 8);
    bf16x8 vf[4];
#pragma unroll
    for (int nf = 0; nf < 4; nf++)
      vf[nf] = *(const bf16x8*)(Vbh + (((size_t)st * 4 + nf) * 64 + l) * 8);

#pragma unroll
    for (int m = 0; m < 4; m++) {
      f32x4 s0 = (f32x4){0.f, 0.f, 0.f, 0.f};
      f32x4 s1 = (f32x4){0.f, 0.f, 0.f, 0.f};
#pragma unroll
      for (int kk = 0; kk < 2; kk++) {
        s0 = __builtin_amdgcn_mfma_f32_16x16x32_bf16(kf[0][kk], qf[m][kk], s0, 0, 0, 0);
        s1 = __builtin_amdgcn_mfma_f32_16x16x32_bf16(kf[1][kk], qf[m][kk], s1, 0, 0, 0);
      }
      f32x4 wA, wB;
      bf16x8 pp;
#pragma unroll
      for (int r = 0; r < 4; r++) {
        float pA = exp2f(s0[r]) * linv[m];
        float pB = exp2f(s1[r]) * linv[m];
        wA[r] = pA;
        wB[r] = pB;
        pp[r] = (__bf16)pA;
        pp[4 + r] = (__bf16)pB;
      }
      // one full 128B L2 line per (row, kt): cols [w*512+kt*32, +32)
      size_t wbase = ((size_t)bh * 2048 + q0 + m * 16 + lr) * 2048 + TA * 16 + g * 4;
      *(f32x4*)(wout + wbase) = wA;
      *(f32x4*)(wout + wbase + 16) = wB;
#pragma unroll
      for (int nf = 0; nf < 4; nf++)
        oacc[m][nf] = __builtin_amdgcn_mfma_f32_16x16x32_bf16(pp, vf[nf],
                                                              oacc[m][nf], 0, 0, 0);
    }
  }

  // ---- cross-wave O reduction (already normalized) ----
  if (w >= 2) {
#pragma unroll
    for (int m = 0; m < 4; m++)
#pragma unroll
      for (int nf = 0; nf < 4; nf++)
#pragma unroll
        for (int r = 0; r < 4; r++)
          Ored[w - 2][m * 16 + g * 4 + r][nf * 16 + lr] = oacc[m][nf][r];
  }
  __syncthreads();
  if (w < 2) {
#pragma unroll
    for (int m = 0; m < 4; m++)
#pragma unroll
      for (int nf = 0; nf < 4; nf++)
#pragma unroll
        for (int r = 0; r < 4; r++)
          Ored[w][m * 16 + g * 4 + r][nf * 16 + lr] += oacc[m][nf][r];
  }
  __syncthreads();

  // epilogue: wave w writes q-rows [w*16, w*16+16); lane = d
  int b = bh >> 4, h = bh & 15;
#pragma unroll
  for (int i = 0; i < 16; i++) {
    int q = w * 16 + i;
    float v = Ored[0][q][l] + Ored[1][q][l];
    aout[(size_t)(b * 2048 + q0 + q) * 1024 + h * 64 + l] = f2bf(v);
  }
}

// ---- host ------------------------------------------------------------------

extern "C" void kernel_launch(void* const* d_in, const int* in_sizes, int n_in,
                              void* d_out, int out_size, void* d_ws, size_t ws_size,
                              hipStream_t stream) {
  const float* x     = (const float*)d_in[0];
  const float* Wqkv  = (const float*)d_in[1];
  const float* bqkv  = (const float*)d_in[2];
  const float* Wproj = (const float*)d_in[3];
  const float* bproj = (const float*)d_in[4];
  const float* wq    = (const float*)d_in[5];
  const float* wk    = (const float*)d_in[6];

  float* out  = (float*)d_out;
  float* wout = out + 4194304;

  char* ws = (char*)d_ws;
  u16* xbf    = (u16*)(ws);                          // 8 MB (reused as aout)
  u16* wqkvT  = (u16*)(ws + (size_t)8  * 1048576);   // 6 MB
  u16* wprojT = (u16*)(ws + (size_t)14 * 1048576);   // 2 MB
  u16* qkvb   = (u16*)(ws + (size_t)16 * 1048576);   // 24 MB
  u16* Qfp    = (u16*)(ws + (size_t)40 * 1048576);   // 8 MB fragment-major
  u16* Kfp    = (u16*)(ws + (size_t)48 * 1048576);   // 8 MB fragment-major
  u16* Vfp    = (u16*)(ws + (size_t)56 * 1048576);   // 8 MB fragment-major
  u16* aout   = xbf;

  k_cvt_x<<<2048, 256, 0, stream>>>(x, xbf, 4194304 / 4);
  k_transpose_cvt<<<dim3(48, 16), 256, 0, stream>>>(Wqkv, wqkvT, 1024, 3072);
  k_transpose_cvt<<<dim3(16, 16), 256, 0, stream>>>(Wproj, wprojT, 1024, 1024);

  // GEMMs now XCD-swizzled (grids 768 and 512 blocks, both % 8 == 0)
  k_gemm_bt<128, true><<<dim3(24, 32), 256, 0, stream>>>(xbf, wqkvT, bqkv, qkvb,
                                                         4096, 3072, 1024);
  k_ropenorm<<<16384, 256, 0, stream>>>(qkvb, wq, wk, Qfp, Kfp);
  k_pack_v<<<dim3(32, 32), 256, 0, stream>>>(qkvb, Vfp);
  // R18/R21 attention — measured best, unchanged
  k_attn<<<dim3(32, 32), 256, 0, stream>>>(Qfp, Kfp, Vfp, wout, aout);
  k_gemm_bt<64, false><<<dim3(8, 64), 256, 0, stream>>>(aout, wprojT, bproj, out,
                                                        4096, 1024, 1024);
}